// Round 1
// baseline (286.753 us; speedup 1.0000x reference)
//
#include <hip/hip_runtime.h>
#include <math.h>

// StateSpaceLayer: diagonal SSM scan
//   s_t = a*s_{t-1} + b*u_t ;  y_t = c*s_t + d*u_t ;  a = tanh(logit_a)
// x: (B=8, T=4096, D=1024) fp32, coefs: (D,) fp32, y: (B,T,D) fp32.
//
// Chunked 2-pass scan: T split into C=64 chunks of L=64.
//   pass1: per-chunk local end state (zero init)   -> ws  (C*B*D floats = 2 MiB)
//   pass2: per-block combine of preceding chunk summaries (uniform loop, L2-hot),
//          then exact recurrence over own chunk, write y.
// Each thread handles 4 consecutive d via float4 -> fully coalesced 1 KiB/wave loads.

#define SSM_B 8
#define SSM_T 4096
#define SSM_D 1024
#define SSM_C 64   // chunks
#define SSM_L 64   // chunk length = T / C

__device__ __forceinline__ float4 f4_fma(float4 a, float4 s, float4 add) {
    return make_float4(fmaf(a.x, s.x, add.x), fmaf(a.y, s.y, add.y),
                       fmaf(a.z, s.z, add.z), fmaf(a.w, s.w, add.w));
}
__device__ __forceinline__ float4 f4_mul(float4 a, float4 b) {
    return make_float4(a.x * b.x, a.y * b.y, a.z * b.z, a.w * b.w);
}

__global__ __launch_bounds__(256) void ssm_pass1(
        const float* __restrict__ x, const float* __restrict__ logit_a,
        const float* __restrict__ bco, float* __restrict__ chunk_end) {
    const int k  = blockIdx.x;          // chunk index
    const int bb = blockIdx.y;          // batch index
    const int d4 = threadIdx.x * 4;     // 256 threads cover D=1024

    float4 la = *(const float4*)(logit_a + d4);
    float4 bv = *(const float4*)(bco + d4);
    float4 a  = make_float4(tanhf(la.x), tanhf(la.y), tanhf(la.z), tanhf(la.w));

    float4 s = make_float4(0.f, 0.f, 0.f, 0.f);
    const float* xp = x + ((size_t)bb * SSM_T + (size_t)k * SSM_L) * SSM_D + d4;
#pragma unroll 8
    for (int t = 0; t < SSM_L; ++t) {
        float4 u = *(const float4*)(xp + (size_t)t * SSM_D);
        s = f4_fma(a, s, f4_mul(bv, u));
    }
    *(float4*)(chunk_end + ((size_t)k * SSM_B + bb) * SSM_D + d4) = s;
}

__global__ __launch_bounds__(256) void ssm_pass2(
        const float* __restrict__ x, const float* __restrict__ logit_a,
        const float* __restrict__ bco, const float* __restrict__ cco,
        const float* __restrict__ dco, const float* __restrict__ chunk_end,
        float* __restrict__ y) {
    const int k  = blockIdx.x;
    const int bb = blockIdx.y;
    const int d4 = threadIdx.x * 4;

    float4 la = *(const float4*)(logit_a + d4);
    float4 bv = *(const float4*)(bco + d4);
    float4 cv = *(const float4*)(cco + d4);
    float4 dv = *(const float4*)(dco + d4);
    float4 a  = make_float4(tanhf(la.x), tanhf(la.y), tanhf(la.z), tanhf(la.w));

    // a^L via repeated squaring (L = 64 = 2^6)
    float4 aL = a;
#pragma unroll
    for (int i = 0; i < 6; ++i) aL = f4_mul(aL, aL);

    // combine preceding chunk summaries: s0 = sum_j a^(L*(k-1-j)) * end_j
    // k is wave-uniform (blockIdx.x) -> no divergence; 2 MiB table is L2-hot.
    float4 s = make_float4(0.f, 0.f, 0.f, 0.f);
    for (int j = 0; j < k; ++j) {
        float4 e = *(const float4*)(chunk_end + ((size_t)j * SSM_B + bb) * SSM_D + d4);
        s = f4_fma(aL, s, e);
    }

    const size_t base = ((size_t)bb * SSM_T + (size_t)k * SSM_L) * SSM_D + d4;
    const float* xp = x + base;
    float*       yp = y + base;
#pragma unroll 8
    for (int t = 0; t < SSM_L; ++t) {
        float4 u = *(const float4*)(xp + (size_t)t * SSM_D);
        s = f4_fma(a, s, f4_mul(bv, u));
        float4 w = f4_fma(cv, s, f4_mul(dv, u));
        *(float4*)(yp + (size_t)t * SSM_D) = w;
    }
}

extern "C" void kernel_launch(void* const* d_in, const int* in_sizes, int n_in,
                              void* d_out, int out_size, void* d_ws, size_t ws_size,
                              hipStream_t stream) {
    const float* x   = (const float*)d_in[0];
    const float* la  = (const float*)d_in[1];
    const float* bco = (const float*)d_in[2];
    const float* cco = (const float*)d_in[3];
    const float* dco = (const float*)d_in[4];
    float* y = (float*)d_out;
    float* chunk_end = (float*)d_ws;   // needs C*B*D*4 = 2 MiB of workspace

    dim3 grid(SSM_C, SSM_B);           // 512 blocks
    dim3 block(256);
    ssm_pass1<<<grid, block, 0, stream>>>(x, la, bco, chunk_end);
    ssm_pass2<<<grid, block, 0, stream>>>(x, la, bco, cco, dco, chunk_end, y);
}

// Round 3
// 275.944 us; speedup vs baseline: 1.0392x; 1.0392x over previous
//
#include <hip/hip_runtime.h>
#include <math.h>

// StateSpaceLayer: diagonal SSM scan
//   s_t = a*s_{t-1} + b*u_t ;  y_t = c*s_t + d*u_t ;  a = tanh(logit_a)
// x: (B=8, T=4096, D=1024) fp32, coefs: (D,) fp32, y: (B,T,D) fp32.
//
// Chunked 2-pass scan: T split into C=128 chunks of L=32.
//   pass1: per-chunk local end state (zero init)   -> ws  (C*B*D floats = 4 MiB)
//   pass2: per-block combine of preceding chunk summaries (uniform loop, L2-hot),
//          then exact recurrence over own chunk from corrected init state, write y.
// R3 = R2 with the nt-store type fixed: __builtin_nontemporal_store needs a
// native clang vector (ext_vector_type), not HIP_vector_type float4.

#define SSM_B 8
#define SSM_T 4096
#define SSM_D 1024
#define SSM_C 128  // chunks
#define SSM_L 32   // chunk length = T / C  (2^5)

typedef float vfloat4 __attribute__((ext_vector_type(4)));

__device__ __forceinline__ float4 f4_fma(float4 a, float4 s, float4 add) {
    return make_float4(fmaf(a.x, s.x, add.x), fmaf(a.y, s.y, add.y),
                       fmaf(a.z, s.z, add.z), fmaf(a.w, s.w, add.w));
}
__device__ __forceinline__ float4 f4_mul(float4 a, float4 b) {
    return make_float4(a.x * b.x, a.y * b.y, a.z * b.z, a.w * b.w);
}
__device__ __forceinline__ void nt_store_f4(float* p, float4 w) {
    vfloat4 v = {w.x, w.y, w.z, w.w};
    __builtin_nontemporal_store(v, (vfloat4*)p);
}

__global__ __launch_bounds__(256) void ssm_pass1(
        const float* __restrict__ x, const float* __restrict__ logit_a,
        const float* __restrict__ bco, float* __restrict__ chunk_end) {
    const int k  = blockIdx.x;          // chunk index
    const int bb = blockIdx.y;          // batch index
    const int d4 = threadIdx.x * 4;     // 256 threads cover D=1024

    float4 la = *(const float4*)(logit_a + d4);
    float4 bv = *(const float4*)(bco + d4);
    float4 a  = make_float4(tanhf(la.x), tanhf(la.y), tanhf(la.z), tanhf(la.w));

    float4 s = make_float4(0.f, 0.f, 0.f, 0.f);
    const float* xp = x + ((size_t)bb * SSM_T + (size_t)k * SSM_L) * SSM_D + d4;
#pragma unroll 8
    for (int t = 0; t < SSM_L; ++t) {
        float4 u = *(const float4*)(xp + (size_t)t * SSM_D);
        s = f4_fma(a, s, f4_mul(bv, u));
    }
    *(float4*)(chunk_end + ((size_t)k * SSM_B + bb) * SSM_D + d4) = s;
}

__global__ __launch_bounds__(256) void ssm_pass2(
        const float* __restrict__ x, const float* __restrict__ logit_a,
        const float* __restrict__ bco, const float* __restrict__ cco,
        const float* __restrict__ dco, const float* __restrict__ chunk_end,
        float* __restrict__ y) {
    const int k  = blockIdx.x;
    const int bb = blockIdx.y;
    const int d4 = threadIdx.x * 4;

    float4 la = *(const float4*)(logit_a + d4);
    float4 bv = *(const float4*)(bco + d4);
    float4 cv = *(const float4*)(cco + d4);
    float4 dv = *(const float4*)(dco + d4);
    float4 a  = make_float4(tanhf(la.x), tanhf(la.y), tanhf(la.z), tanhf(la.w));

    // a^L via repeated squaring (L = 32 = 2^5)
    float4 aL = a;
#pragma unroll
    for (int i = 0; i < 5; ++i) aL = f4_mul(aL, aL);

    // combine preceding chunk summaries: s0 = sum_j a^(L*(k-1-j)) * end_j
    // k is wave-uniform (blockIdx.x) -> no divergence; 4 MiB table is L2/L3-hot.
    float4 s = make_float4(0.f, 0.f, 0.f, 0.f);
    for (int j = 0; j < k; ++j) {
        float4 e = *(const float4*)(chunk_end + ((size_t)j * SSM_B + bb) * SSM_D + d4);
        s = f4_fma(aL, s, e);
    }

    const size_t base = ((size_t)bb * SSM_T + (size_t)k * SSM_L) * SSM_D + d4;
    const float* xp = x + base;
    float*       yp = y + base;
#pragma unroll 8
    for (int t = 0; t < SSM_L; ++t) {
        float4 u = *(const float4*)(xp + (size_t)t * SSM_D);
        s = f4_fma(a, s, f4_mul(bv, u));
        float4 w = f4_fma(cv, s, f4_mul(dv, u));
        // nt store: don't let y allocate in L2/L3 and evict the x lines
        // pass2 still needs to re-read.
        nt_store_f4(yp + (size_t)t * SSM_D, w);
    }
}

extern "C" void kernel_launch(void* const* d_in, const int* in_sizes, int n_in,
                              void* d_out, int out_size, void* d_ws, size_t ws_size,
                              hipStream_t stream) {
    const float* x   = (const float*)d_in[0];
    const float* la  = (const float*)d_in[1];
    const float* bco = (const float*)d_in[2];
    const float* cco = (const float*)d_in[3];
    const float* dco = (const float*)d_in[4];
    float* y = (float*)d_out;
    float* chunk_end = (float*)d_ws;   // needs C*B*D*4 = 4 MiB of workspace

    dim3 grid(SSM_C, SSM_B);           // 1024 blocks -> 4 blocks/CU, all co-resident
    dim3 block(256);
    ssm_pass1<<<grid, block, 0, stream>>>(x, la, bco, chunk_end);
    ssm_pass2<<<grid, block, 0, stream>>>(x, la, bco, cco, dco, chunk_end, y);
}

// Round 4
// 274.649 us; speedup vs baseline: 1.0441x; 1.0047x over previous
//
#include <hip/hip_runtime.h>
#include <math.h>

// StateSpaceLayer: diagonal SSM scan
//   s_t = a*s_{t-1} + b*u_t ;  y_t = c*s_t + d*u_t ;  a = tanh(logit_a)
// x: (B=8, T=4096, D=1024) fp32, coefs: (D,) fp32, y: (B,T,D) fp32.
//
// Chunked 3-kernel scan: T split into C=128 chunks of L=32.
//   pass1 : per-chunk local end state (zero init)      -> ws.chunk_end (4 MiB)
//   prefix: serial per-channel scan over chunk ends    -> ws.chunk_start (4 MiB)
//           (kills R3's quadratic combine: was ~254 MiB of L2/L3 reads + a
//            ~64-iter dependent-FMA prologue in every pass2 block)
//   pass2 : load own start state (one 16B load), exact recurrence, write y.
// nt loads for x in pass2 (last use), nt stores for y (don't evict L3-resident x).

#define SSM_B 8
#define SSM_T 4096
#define SSM_D 1024
#define SSM_C 128  // chunks
#define SSM_L 32   // chunk length = T / C  (2^5)

typedef float vfloat4 __attribute__((ext_vector_type(4)));

__device__ __forceinline__ float4 f4_fma(float4 a, float4 s, float4 add) {
    return make_float4(fmaf(a.x, s.x, add.x), fmaf(a.y, s.y, add.y),
                       fmaf(a.z, s.z, add.z), fmaf(a.w, s.w, add.w));
}
__device__ __forceinline__ float4 f4_mul(float4 a, float4 b) {
    return make_float4(a.x * b.x, a.y * b.y, a.z * b.z, a.w * b.w);
}
__device__ __forceinline__ void nt_store_f4(float* p, float4 w) {
    vfloat4 v = {w.x, w.y, w.z, w.w};
    __builtin_nontemporal_store(v, (vfloat4*)p);
}
__device__ __forceinline__ float4 nt_load_f4(const float* p) {
    vfloat4 v = __builtin_nontemporal_load((const vfloat4*)p);
    return make_float4(v.x, v.y, v.z, v.w);
}

__global__ __launch_bounds__(256) void ssm_pass1(
        const float* __restrict__ x, const float* __restrict__ logit_a,
        const float* __restrict__ bco, float* __restrict__ chunk_end) {
    const int k  = blockIdx.x;          // chunk index
    const int bb = blockIdx.y;          // batch index
    const int d4 = threadIdx.x * 4;     // 256 threads cover D=1024

    float4 la = *(const float4*)(logit_a + d4);
    float4 bv = *(const float4*)(bco + d4);
    float4 a  = make_float4(tanhf(la.x), tanhf(la.y), tanhf(la.z), tanhf(la.w));

    float4 s = make_float4(0.f, 0.f, 0.f, 0.f);
    const float* xp = x + ((size_t)bb * SSM_T + (size_t)k * SSM_L) * SSM_D + d4;
#pragma unroll 8
    for (int t = 0; t < SSM_L; ++t) {
        float4 u = *(const float4*)(xp + (size_t)t * SSM_D);
        s = f4_fma(a, s, f4_mul(bv, u));
    }
    *(float4*)(chunk_end + ((size_t)k * SSM_B + bb) * SSM_D + d4) = s;
}

// One scalar thread per (batch, channel): exclusive scan over chunk end-states.
//   chunk_start[k] = sum_{j<k} a^(L*(k-1-j)) * chunk_end[j]
// 8192 threads, 4 MiB read + 4 MiB write, loads independent -> pipelineable.
__global__ __launch_bounds__(256) void ssm_prefix(
        const float* __restrict__ logit_a,
        const float* __restrict__ chunk_end,
        float* __restrict__ chunk_start) {
    const int tid = blockIdx.x * 256 + threadIdx.x;  // [0, B*D)
    const int bb  = tid >> 10;                       // D = 1024
    const int d   = tid & (SSM_D - 1);

    float a  = tanhf(logit_a[d]);
    float aL = a;
#pragma unroll
    for (int i = 0; i < 5; ++i) aL *= aL;            // a^L, L = 32

    float s = 0.f;
    const size_t stride = (size_t)SSM_B * SSM_D;
    size_t idx = (size_t)bb * SSM_D + d;
#pragma unroll 4
    for (int j = 0; j < SSM_C; ++j) {
        chunk_start[idx] = s;
        s = fmaf(aL, s, chunk_end[idx]);
        idx += stride;
    }
}

__global__ __launch_bounds__(256) void ssm_pass2(
        const float* __restrict__ x, const float* __restrict__ logit_a,
        const float* __restrict__ bco, const float* __restrict__ cco,
        const float* __restrict__ dco, const float* __restrict__ chunk_start,
        float* __restrict__ y) {
    const int k  = blockIdx.x;
    const int bb = blockIdx.y;
    const int d4 = threadIdx.x * 4;

    float4 la = *(const float4*)(logit_a + d4);
    float4 bv = *(const float4*)(bco + d4);
    float4 cv = *(const float4*)(cco + d4);
    float4 dv = *(const float4*)(dco + d4);
    float4 a  = make_float4(tanhf(la.x), tanhf(la.y), tanhf(la.z), tanhf(la.w));

    // initial state for this chunk: one coalesced 16B load per thread
    float4 s = *(const float4*)(chunk_start + ((size_t)k * SSM_B + bb) * SSM_D + d4);

    const size_t base = ((size_t)bb * SSM_T + (size_t)k * SSM_L) * SSM_D + d4;
    const float* xp = x + base;
    float*       yp = y + base;
#pragma unroll 8
    for (int t = 0; t < SSM_L; ++t) {
        // nt load: last use of x — hit L3 if resident, don't re-pollute
        float4 u = nt_load_f4(xp + (size_t)t * SSM_D);
        s = f4_fma(a, s, f4_mul(bv, u));
        float4 w = f4_fma(cv, s, f4_mul(dv, u));
        // nt store: y is write-once — don't evict L3-resident x
        nt_store_f4(yp + (size_t)t * SSM_D, w);
    }
}

extern "C" void kernel_launch(void* const* d_in, const int* in_sizes, int n_in,
                              void* d_out, int out_size, void* d_ws, size_t ws_size,
                              hipStream_t stream) {
    const float* x   = (const float*)d_in[0];
    const float* la  = (const float*)d_in[1];
    const float* bco = (const float*)d_in[2];
    const float* cco = (const float*)d_in[3];
    const float* dco = (const float*)d_in[4];
    float* y = (float*)d_out;
    float* chunk_end   = (float*)d_ws;                              // 4 MiB
    float* chunk_start = (float*)d_ws + (size_t)SSM_C * SSM_B * SSM_D; // 4 MiB

    dim3 grid(SSM_C, SSM_B);           // 1024 blocks -> 4 blocks/CU
    dim3 block(256);
    ssm_pass1<<<grid, block, 0, stream>>>(x, la, bco, chunk_end);
    ssm_prefix<<<dim3((SSM_B * SSM_D) / 256), block, 0, stream>>>(la, chunk_end, chunk_start);
    ssm_pass2<<<grid, block, 0, stream>>>(x, la, bco, cco, dco, chunk_start, y);
}